// Round 3
// baseline (192.901 us; speedup 1.0000x reference)
//
#include <hip/hip_runtime.h>

// LIF recurrence: u_t = decay*u_{t-1} + x_t - o_{t-1}*VTH ; o_t = (u_t - VTH > 0)
// x: [B=64, N=4096, T=100] f32, T contiguous (400 B per neuron row).
//
// R3: 256-thread blocks (4 waves) own 256 neurons = four 64-neuron sub-slabs
// (25.6 KB contiguous each). Double-buffered LDS (2x25.6 KB = 51.2 KB ->
// 3 blocks/CU = 12 waves/CU). Each sub-slab's 25 global_load_lds DMA instrs
// are split across all 4 waves (so every resident wave keeps loads in
// flight -- R1/R2 showed per-wave memory throughput caps at ~1 B/cyc; waves
// are the currency). Compute of sub-slab p is done by wave p (in-place
// x->o overwrite in LDS), then all waves cooperatively store it with
// line-perfect 1 KB/instr stores. 3 staggered blocks/CU overlap the
// barrier-drain phases.

#define VTH 0.5f
#define T_STEPS 100
#define NSUB 64                   // neurons per sub-slab
#define SUB_FLOATS (NSUB * T_STEPS)   // 6400 floats = 25.6 KB
#define K_INSTR 25                // 1 KB wave-wide transfers per sub-slab
#define SUBS 4                    // sub-slabs per block

__global__ __launch_bounds__(256) void lif_kernel(const float* __restrict__ x,
                                                  const float* __restrict__ decay_p,
                                                  float* __restrict__ out,
                                                  int n_neurons) {
    __shared__ float buf[2][SUB_FLOATS];   // 51,200 B

    const int tid = threadIdx.x;
    const int wave = tid >> 6;
    const int lane = tid & 63;
    // per-wave slice of the 25 transfers: 6,6,6,7
    const int kbeg = (K_INSTR * wave) / 4;
    const int kend = (K_INSTR * (wave + 1)) / 4;

    const size_t block_f = (size_t)blockIdx.x * (SUBS * SUB_FLOATS);
    const float decay = decay_p[0];

    // ---- stage sub-slab p into buf[bi]: lane-contiguous 16 B -> flat slab copy
    auto stage = [&](int p, int bi) {
        const float* src = x + block_f + (size_t)p * SUB_FLOATS;
        for (int k = kbeg; k < kend; ++k) {
            __builtin_amdgcn_global_load_lds(
                (const __attribute__((address_space(1))) float*)(src + k * 256 + lane * 4),
                (__attribute__((address_space(3))) float*)&buf[bi][k * 256],
                16, 0, 0);
        }
    };

    stage(0, 0);

    #pragma unroll
    for (int p = 0; p < SUBS; ++p) {
        if (p < SUBS - 1) stage(p + 1, (p + 1) & 1);
        __syncthreads();   // (A) sub-slab p resident (drains p+1 too — structural)

        if (wave == p) {
            // compute: thread `lane` owns neuron p*64+lane; row = float4 [lane*25, +25)
            float4* b4 = (float4*)buf[p & 1];
            float u = 0.0f, o = 0.0f;
            #pragma unroll
            for (int i = 0; i < K_INSTR; ++i) {
                float4 v = b4[lane * K_INSTR + i];
                u = decay * u + v.x - o * VTH; o = (u > VTH) ? 1.0f : 0.0f; v.x = o;
                u = decay * u + v.y - o * VTH; o = (u > VTH) ? 1.0f : 0.0f; v.y = o;
                u = decay * u + v.z - o * VTH; o = (u > VTH) ? 1.0f : 0.0f; v.z = o;
                u = decay * u + v.w - o * VTH; o = (u > VTH) ? 1.0f : 0.0f; v.w = o;
                b4[lane * K_INSTR + i] = v;
            }
        }
        __syncthreads();   // (B) outputs visible to all waves

        // cooperative line-perfect store of sub-slab p
        {
            float4* o4 = (float4*)(out + block_f + (size_t)p * SUB_FLOATS);
            float4* b4 = (float4*)buf[p & 1];
            for (int k = kbeg; k < kend; ++k) {
                o4[k * 64 + lane] = b4[k * 64 + lane];
            }
        }
        if (p < SUBS - 1)
            __syncthreads();  // (C) LDS reads of buf[p&1] done before stage(p+2) overwrites it
    }
}

extern "C" void kernel_launch(void* const* d_in, const int* in_sizes, int n_in,
                              void* d_out, int out_size, void* d_ws, size_t ws_size,
                              hipStream_t stream) {
    const float* x = (const float*)d_in[0];
    const float* decay = (const float*)d_in[1];
    float* out = (float*)d_out;

    const int n_neurons = in_sizes[0] / T_STEPS;        // 262,144
    const int grid = n_neurons / (SUBS * NSUB);         // 1024 blocks of 256 threads

    lif_kernel<<<grid, 256, 0, stream>>>(x, decay, out, n_neurons);
}